// Round 1
// baseline (1111.516 us; speedup 1.0000x reference)
//
#include <hip/hip_runtime.h>
#include <hip/hip_bf16.h>

#define B_IMG 4
#define PRE_NMS 4096
#define POST_NMS 500
#define CAND_CAP 8192

__device__ __forceinline__ unsigned key_of(float f) {
    unsigned u = __float_as_uint(f);
    return (u & 0x80000000u) ? ~u : (u | 0x80000000u);
}

// ---------------- init ----------------
__global__ void init_kernel(uint2* state, unsigned* hist, unsigned* count) {
    int t = blockIdx.x * blockDim.x + threadIdx.x;
    if (t < B_IMG) { state[t] = make_uint2(0u, (unsigned)PRE_NMS); count[t] = 0u; }
    if (t < 4 * B_IMG * 256) hist[t] = 0u;
}

// ---------------- radix-select histogram ----------------
__global__ void hist_kernel(const float* __restrict__ obj, const uint2* __restrict__ state,
                            unsigned* __restrict__ hist, int pass, int A) {
    int b = blockIdx.y;
    __shared__ unsigned h[256];
    int t = threadIdx.x;
    if (t < 256) h[t] = 0u;
    __syncthreads();
    unsigned prefix = state[b].x;
    const float* o = obj + (size_t)b * A;
    int stride = gridDim.x * blockDim.x;
    for (int i = blockIdx.x * blockDim.x + t; i < A; i += stride) {
        unsigned key = key_of(o[i]);
        bool match = (pass == 0) || ((key >> (32 - 8 * pass)) == prefix);
        if (match) atomicAdd(&h[(key >> (24 - 8 * pass)) & 255u], 1u);
    }
    __syncthreads();
    if (t < 256 && h[t]) atomicAdd(&hist[(pass * B_IMG + b) * 256 + t], h[t]);
}

// ---------------- radix-select scan ----------------
__global__ void scan_kernel(uint2* state, const unsigned* __restrict__ hist, int pass) {
    int b = threadIdx.x;
    if (b < B_IMG) {
        const unsigned* h = hist + (pass * B_IMG + b) * 256;
        unsigned kneed = state[b].y;
        unsigned cum = 0;
        int d;
        for (d = 255; d >= 0; d--) {
            unsigned c = h[d];
            if (cum + c >= kneed) break;
            cum += c;
        }
        state[b].x = (state[b].x << 8) | (unsigned)d;
        state[b].y = kneed - cum;
    }
}

// ---------------- gather candidates >= threshold ----------------
__global__ void gather_kernel(const float* __restrict__ obj, const uint2* __restrict__ state,
                              unsigned long long* __restrict__ cand, unsigned* __restrict__ count, int A) {
    int b = blockIdx.y;
    unsigned T = state[b].x;
    const float* o = obj + (size_t)b * A;
    int stride = gridDim.x * blockDim.x;
    for (int i = blockIdx.x * blockDim.x + threadIdx.x; i < A; i += stride) {
        unsigned key = key_of(o[i]);
        if (key >= T) {
            unsigned pos = atomicAdd(&count[b], 1u);
            if (pos < CAND_CAP)
                cand[(size_t)b * CAND_CAP + pos] =
                    ((unsigned long long)key << 32) | (unsigned)(0xFFFFFFFFu - (unsigned)i);
        }
    }
}

// ---------------- bitonic sort of candidates (desc), emit topk ----------------
__global__ void __launch_bounds__(1024) sort_kernel(const unsigned long long* __restrict__ cand,
                                                    const unsigned* __restrict__ count,
                                                    unsigned* __restrict__ topk_idx,
                                                    const float* __restrict__ obj,
                                                    float* __restrict__ s_top, int A) {
    __shared__ unsigned long long s[CAND_CAP];
    int b = blockIdx.x;
    int t = threadIdx.x;
    unsigned cnt = count[b];
    if (cnt > CAND_CAP) cnt = CAND_CAP;
    const unsigned long long* C = cand + (size_t)b * CAND_CAP;
    for (int i = t; i < CAND_CAP; i += 1024) s[i] = (i < (int)cnt) ? C[i] : 0ull;
    __syncthreads();
    for (int k = 2; k <= CAND_CAP; k <<= 1) {
        for (int j = k >> 1; j > 0; j >>= 1) {
            for (int i = t; i < CAND_CAP; i += 1024) {
                int l = i ^ j;
                if (l > i) {
                    unsigned long long a = s[i], c = s[l];
                    bool up = ((i & k) == 0);
                    if (up ? (a < c) : (a > c)) { s[i] = c; s[l] = a; }
                }
            }
            __syncthreads();
        }
    }
    for (int r = t; r < PRE_NMS; r += 1024) {
        unsigned long long v = s[r];
        unsigned idx = 0xFFFFFFFFu - (unsigned)(v & 0xFFFFFFFFull);
        topk_idx[b * PRE_NMS + r] = idx;
        float x = obj[(size_t)b * A + idx];
        s_top[b * PRE_NMS + r] = 1.0f / (1.0f + expf(-x));
    }
}

// ---------------- decode boxes ----------------
__global__ void decode_kernel(const float* __restrict__ anchors, const float* __restrict__ reg,
                              const unsigned* __restrict__ topk_idx, float* __restrict__ boxes,
                              float* __restrict__ X1, float* __restrict__ X2,
                              float* __restrict__ Y1, float* __restrict__ Y2,
                              float* __restrict__ AREA, int A) {
    int b = blockIdx.y;
    int r = blockIdx.x * 256 + threadIdx.x;
    if (r >= PRE_NMS) return;
    unsigned idx = topk_idx[b * PRE_NMS + r];
    const float* an = anchors + ((size_t)b * A + idx) * 7;
    const float* rg = reg + ((size_t)b * A + idx) * 7;
    float xa = an[0], ya = an[1], za = an[2], wa = an[3], la = an[4], ha = an[5], ra = an[6];
    float diag = sqrtf(wa * wa + la * la);
    float xg = rg[0] * diag + xa;
    float yg = rg[1] * diag + ya;
    float zg = rg[2] * ha + za;
    float wg = expf(rg[3]) * wa;
    float lg = expf(rg[4]) * la;
    float hg = expf(rg[5]) * ha;
    float rr = rg[6] + ra;
    float* o = boxes + ((size_t)b * PRE_NMS + r) * 7;
    o[0] = xg; o[1] = yg; o[2] = zg; o[3] = wg; o[4] = lg; o[5] = hg; o[6] = rr;
    int q = b * PRE_NMS + r;
    X1[q] = xg - wg * 0.5f;
    X2[q] = xg + wg * 0.5f;
    Y1[q] = yg - lg * 0.5f;
    Y2[q] = yg + lg * 0.5f;
    AREA[q] = wg * lg;
}

// ---------------- suppression bitmask ----------------
__global__ void mask_kernel(const float* __restrict__ X1, const float* __restrict__ X2,
                            const float* __restrict__ Y1, const float* __restrict__ Y2,
                            const float* __restrict__ AREA, unsigned long long* __restrict__ mask) {
    int b = blockIdx.y;
    int t = blockIdx.x * 256 + threadIdx.x;   // 1024 blocks * 256 = 262144 = 4096*64
    int i = t & (PRE_NMS - 1);
    int w = t >> 12;
    int q0 = b * PRE_NMS;
    float x1i = X1[q0 + i], x2i = X2[q0 + i];
    float y1i = Y1[q0 + i], y2i = Y2[q0 + i];
    float ai = AREA[q0 + i];
    unsigned long long word = 0ull;
    int jbase = w << 6;
#pragma unroll 4
    for (int k = 0; k < 64; k++) {
        int j = jbase + k;
        float iw = fminf(x2i, X2[q0 + j]) - fmaxf(x1i, X1[q0 + j]);
        iw = fmaxf(iw, 0.0f);
        float ih = fminf(y2i, Y2[q0 + j]) - fmaxf(y1i, Y1[q0 + j]);
        ih = fmaxf(ih, 0.0f);
        float inter = iw * ih;
        float den = ai + AREA[q0 + j] - inter + 1e-6f;
        float iou = inter / den;
        word |= ((unsigned long long)((iou > 0.7f) && (j > i))) << k;
    }
    mask[((size_t)b * PRE_NMS + i) * 64 + w] = word;
}

// ---------------- sequential greedy NMS resolve ----------------
__global__ void nms_kernel(const unsigned long long* __restrict__ mask,
                           unsigned long long* __restrict__ keep_out) {
    int b = blockIdx.x;
    int lane = threadIdx.x;  // 64 lanes, lane owns keep word `lane`
    const unsigned long long* M = mask + (size_t)b * PRE_NMS * 64;
    unsigned long long keep = ~0ull;
    unsigned long long p0 = M[0 * 64 + lane];
    unsigned long long p1 = M[1 * 64 + lane];
    unsigned long long p2 = M[2 * 64 + lane];
    unsigned long long p3 = M[3 * 64 + lane];
    for (int i = 0; i < PRE_NMS; i++) {
        unsigned long long row = p0;
        p0 = p1; p1 = p2; p2 = p3;
        p3 = (i + 4 < PRE_NMS) ? M[(size_t)(i + 4) * 64 + lane] : 0ull;
        unsigned long long kw = __shfl(keep, i >> 6);
        if ((kw >> (i & 63)) & 1ull) keep &= ~row;
    }
    keep_out[b * 64 + lane] = keep;
}

// ---------------- select top-500 and write output ----------------
__global__ void select_write_kernel(const unsigned long long* __restrict__ keep,
                                    const float* __restrict__ boxes,
                                    const float* __restrict__ s_top,
                                    float* __restrict__ out) {
    int b = blockIdx.x;
    __shared__ int cnts[64];
    __shared__ int bases[65];
    __shared__ int sel[POST_NMS];
    int t = threadIdx.x;  // 512
    if (t < 64) cnts[t] = __popcll(keep[b * 64 + t]);
    __syncthreads();
    if (t == 0) {
        int acc = 0;
        for (int w = 0; w < 64; w++) { bases[w] = acc; acc += cnts[w]; }
        bases[64] = acc;
    }
    __syncthreads();
    if (t < 64) {
        unsigned long long kw = keep[b * 64 + t];
        int K_total = bases[64];
        int kr = bases[t];
        int ur = t * 64 - bases[t];
        for (int k = 0; k < 64; k++) {
            int i = t * 64 + k;
            if ((kw >> k) & 1ull) {
                if (kr < POST_NMS) sel[kr] = i;
                kr++;
            } else {
                int pos = K_total + ur;
                if (pos < POST_NMS) sel[pos] = i;
                ur++;
            }
        }
    }
    __syncthreads();
    for (int r = t; r < POST_NMS; r += 512) {
        int i = sel[r];
        const float* bx = boxes + ((size_t)b * PRE_NMS + i) * 7;
        float* o = out + ((size_t)b * POST_NMS + r) * 8;
#pragma unroll
        for (int c = 0; c < 7; c++) o[c] = bx[c];
        o[7] = s_top[b * PRE_NMS + i];
    }
}

extern "C" void kernel_launch(void* const* d_in, const int* in_sizes, int n_in,
                              void* d_out, int out_size, void* d_ws, size_t ws_size,
                              hipStream_t stream) {
    const float* anchors = (const float*)d_in[0];
    const float* obj = (const float*)d_in[1];
    const float* reg = (const float*)d_in[2];
    float* out = (float*)d_out;
    const int A = in_sizes[1] / B_IMG;

    auto align = [](size_t x) { return (x + 255) & ~(size_t)255; };
    char* p = (char*)d_ws;
    uint2* state = (uint2*)p;                 p += align(B_IMG * sizeof(uint2));
    unsigned* hist = (unsigned*)p;            p += align(4 * B_IMG * 256 * sizeof(unsigned));
    unsigned* count = (unsigned*)p;           p += align(B_IMG * sizeof(unsigned));
    unsigned long long* cand = (unsigned long long*)p; p += align((size_t)B_IMG * CAND_CAP * 8);
    unsigned* topk = (unsigned*)p;            p += align((size_t)B_IMG * PRE_NMS * 4);
    float* s_top = (float*)p;                 p += align((size_t)B_IMG * PRE_NMS * 4);
    float* boxes = (float*)p;                 p += align((size_t)B_IMG * PRE_NMS * 7 * 4);
    float* X1 = (float*)p;                    p += align((size_t)B_IMG * PRE_NMS * 4);
    float* X2 = (float*)p;                    p += align((size_t)B_IMG * PRE_NMS * 4);
    float* Y1 = (float*)p;                    p += align((size_t)B_IMG * PRE_NMS * 4);
    float* Y2 = (float*)p;                    p += align((size_t)B_IMG * PRE_NMS * 4);
    float* AREA = (float*)p;                  p += align((size_t)B_IMG * PRE_NMS * 4);
    unsigned long long* mask = (unsigned long long*)p; p += align((size_t)B_IMG * PRE_NMS * 64 * 8);
    unsigned long long* keep = (unsigned long long*)p; p += align((size_t)B_IMG * 64 * 8);

    init_kernel<<<16, 256, 0, stream>>>(state, hist, count);
    for (int pass = 0; pass < 4; pass++) {
        hist_kernel<<<dim3(256, B_IMG), 256, 0, stream>>>(obj, state, hist, pass, A);
        scan_kernel<<<1, 64, 0, stream>>>(state, hist, pass);
    }
    gather_kernel<<<dim3(256, B_IMG), 256, 0, stream>>>(obj, state, cand, count, A);
    sort_kernel<<<B_IMG, 1024, 0, stream>>>(cand, count, topk, obj, s_top, A);
    decode_kernel<<<dim3(PRE_NMS / 256, B_IMG), 256, 0, stream>>>(anchors, reg, topk, boxes,
                                                                  X1, X2, Y1, Y2, AREA, A);
    mask_kernel<<<dim3(PRE_NMS * 64 / 256, B_IMG), 256, 0, stream>>>(X1, X2, Y1, Y2, AREA, mask);
    nms_kernel<<<B_IMG, 64, 0, stream>>>(mask, keep);
    select_write_kernel<<<B_IMG, 512, 0, stream>>>(keep, boxes, s_top, out);
}

// Round 2
// 623.023 us; speedup vs baseline: 1.7841x; 1.7841x over previous
//
#include <hip/hip_runtime.h>
#include <hip/hip_bf16.h>

#define B_IMG 4
#define PRE_NMS 4096
#define POST_NMS 500
#define CAND_CAP 8192

__device__ __forceinline__ unsigned key_of(float f) {
    unsigned u = __float_as_uint(f);
    return (u & 0x80000000u) ? ~u : (u | 0x80000000u);
}

// ---------------- init ----------------
__global__ void init_kernel(uint2* state, unsigned* hist, unsigned* count) {
    int t = blockIdx.x * blockDim.x + threadIdx.x;
    if (t < B_IMG) { state[t] = make_uint2(0u, (unsigned)PRE_NMS); count[t] = 0u; }
    if (t < 4 * B_IMG * 256) hist[t] = 0u;
}

// ---------------- radix-select histogram ----------------
__global__ void hist_kernel(const float* __restrict__ obj, const uint2* __restrict__ state,
                            unsigned* __restrict__ hist, int pass, int A) {
    int b = blockIdx.y;
    __shared__ unsigned h[256];
    int t = threadIdx.x;
    if (t < 256) h[t] = 0u;
    __syncthreads();
    unsigned prefix = state[b].x;
    const float* o = obj + (size_t)b * A;
    int stride = gridDim.x * blockDim.x;
    for (int i = blockIdx.x * blockDim.x + t; i < A; i += stride) {
        unsigned key = key_of(o[i]);
        bool match = (pass == 0) || ((key >> (32 - 8 * pass)) == prefix);
        if (match) atomicAdd(&h[(key >> (24 - 8 * pass)) & 255u], 1u);
    }
    __syncthreads();
    if (t < 256 && h[t]) atomicAdd(&hist[(pass * B_IMG + b) * 256 + t], h[t]);
}

// ---------------- radix-select scan ----------------
__global__ void scan_kernel(uint2* state, const unsigned* __restrict__ hist, int pass) {
    int b = threadIdx.x;
    if (b < B_IMG) {
        const unsigned* h = hist + (pass * B_IMG + b) * 256;
        unsigned kneed = state[b].y;
        unsigned cum = 0;
        int d;
        for (d = 255; d >= 0; d--) {
            unsigned c = h[d];
            if (cum + c >= kneed) break;
            cum += c;
        }
        state[b].x = (state[b].x << 8) | (unsigned)d;
        state[b].y = kneed - cum;
    }
}

// ---------------- gather candidates >= threshold ----------------
__global__ void gather_kernel(const float* __restrict__ obj, const uint2* __restrict__ state,
                              unsigned long long* __restrict__ cand, unsigned* __restrict__ count, int A) {
    int b = blockIdx.y;
    unsigned T = state[b].x;
    const float* o = obj + (size_t)b * A;
    int stride = gridDim.x * blockDim.x;
    for (int i = blockIdx.x * blockDim.x + threadIdx.x; i < A; i += stride) {
        unsigned key = key_of(o[i]);
        if (key >= T) {
            unsigned pos = atomicAdd(&count[b], 1u);
            if (pos < CAND_CAP)
                cand[(size_t)b * CAND_CAP + pos] =
                    ((unsigned long long)key << 32) | (unsigned)(0xFFFFFFFFu - (unsigned)i);
        }
    }
}

// ---------------- bitonic sort of candidates (desc), emit topk ----------------
__global__ void __launch_bounds__(1024) sort_kernel(const unsigned long long* __restrict__ cand,
                                                    const unsigned* __restrict__ count,
                                                    unsigned* __restrict__ topk_idx,
                                                    const float* __restrict__ obj,
                                                    float* __restrict__ s_top, int A) {
    __shared__ unsigned long long s[CAND_CAP];
    int b = blockIdx.x;
    int t = threadIdx.x;
    unsigned cnt = count[b];
    if (cnt > CAND_CAP) cnt = CAND_CAP;
    const unsigned long long* C = cand + (size_t)b * CAND_CAP;
    for (int i = t; i < CAND_CAP; i += 1024) s[i] = (i < (int)cnt) ? C[i] : 0ull;
    __syncthreads();
    for (int k = 2; k <= CAND_CAP; k <<= 1) {
        for (int j = k >> 1; j > 0; j >>= 1) {
            for (int i = t; i < CAND_CAP; i += 1024) {
                int l = i ^ j;
                if (l > i) {
                    unsigned long long a = s[i], c = s[l];
                    bool up = ((i & k) == 0);
                    if (up ? (a < c) : (a > c)) { s[i] = c; s[l] = a; }
                }
            }
            __syncthreads();
        }
    }
    for (int r = t; r < PRE_NMS; r += 1024) {
        unsigned long long v = s[r];
        unsigned idx = 0xFFFFFFFFu - (unsigned)(v & 0xFFFFFFFFull);
        topk_idx[b * PRE_NMS + r] = idx;
        float x = obj[(size_t)b * A + idx];
        s_top[b * PRE_NMS + r] = 1.0f / (1.0f + expf(-x));
    }
}

// ---------------- decode boxes ----------------
__global__ void decode_kernel(const float* __restrict__ anchors, const float* __restrict__ reg,
                              const unsigned* __restrict__ topk_idx, float* __restrict__ boxes,
                              float* __restrict__ X1, float* __restrict__ X2,
                              float* __restrict__ Y1, float* __restrict__ Y2,
                              float* __restrict__ AREA, int A) {
    int b = blockIdx.y;
    int r = blockIdx.x * 256 + threadIdx.x;
    if (r >= PRE_NMS) return;
    unsigned idx = topk_idx[b * PRE_NMS + r];
    const float* an = anchors + ((size_t)b * A + idx) * 7;
    const float* rg = reg + ((size_t)b * A + idx) * 7;
    float xa = an[0], ya = an[1], za = an[2], wa = an[3], la = an[4], ha = an[5], ra = an[6];
    float diag = sqrtf(wa * wa + la * la);
    float xg = rg[0] * diag + xa;
    float yg = rg[1] * diag + ya;
    float zg = rg[2] * ha + za;
    float wg = expf(rg[3]) * wa;
    float lg = expf(rg[4]) * la;
    float hg = expf(rg[5]) * ha;
    float rr = rg[6] + ra;
    float* o = boxes + ((size_t)b * PRE_NMS + r) * 7;
    o[0] = xg; o[1] = yg; o[2] = zg; o[3] = wg; o[4] = lg; o[5] = hg; o[6] = rr;
    int q = b * PRE_NMS + r;
    X1[q] = xg - wg * 0.5f;
    X2[q] = xg + wg * 0.5f;
    Y1[q] = yg - lg * 0.5f;
    Y2[q] = yg + lg * 0.5f;
    AREA[q] = wg * lg;
}

// ---------------- suppression bitmask ----------------
__global__ void mask_kernel(const float* __restrict__ X1, const float* __restrict__ X2,
                            const float* __restrict__ Y1, const float* __restrict__ Y2,
                            const float* __restrict__ AREA, unsigned long long* __restrict__ mask) {
    int b = blockIdx.y;
    int t = blockIdx.x * 256 + threadIdx.x;   // 1024 blocks * 256 = 262144 = 4096*64
    int i = t & (PRE_NMS - 1);
    int w = t >> 12;
    int q0 = b * PRE_NMS;
    float x1i = X1[q0 + i], x2i = X2[q0 + i];
    float y1i = Y1[q0 + i], y2i = Y2[q0 + i];
    float ai = AREA[q0 + i];
    unsigned long long word = 0ull;
    int jbase = w << 6;
#pragma unroll 4
    for (int k = 0; k < 64; k++) {
        int j = jbase + k;
        float iw = fminf(x2i, X2[q0 + j]) - fmaxf(x1i, X1[q0 + j]);
        iw = fmaxf(iw, 0.0f);
        float ih = fminf(y2i, Y2[q0 + j]) - fmaxf(y1i, Y1[q0 + j]);
        ih = fmaxf(ih, 0.0f);
        float inter = iw * ih;
        float den = ai + AREA[q0 + j] - inter + 1e-6f;
        float iou = inter / den;
        word |= ((unsigned long long)((iou > 0.7f) && (j > i))) << k;
    }
    mask[((size_t)b * PRE_NMS + i) * 64 + w] = word;
}

// ---------------- tiled greedy NMS resolve ----------------
// One wave per image. Lane l owns keep word l. Serial over 64 tiles of 64 boxes.
// Per tile: resolve intra-tile greedy via diagonal words (ballot fast path),
// then apply kept rows to all later words with a register-buffered 64-row batch.
// Double-buffered rows so tile w+1 loads overlap tile w compute.
#define LOAD_TILE(BUF, WT) do {                                               \
    const unsigned long long* _base = Mb + ((size_t)(WT) << 12) + lane;       \
    _Pragma("unroll")                                                         \
    for (int _k = 0; _k < 64; _k++) BUF[_k] = _base[(size_t)_k << 6];         \
} while (0)

#define LOAD_D(DST, WT) (DST) = Mb[((size_t)(WT) << 12) + ((size_t)lane << 6) + (WT)]

#define PROCESS(W, CURB, DCUR, NXTB, DNXT) do {                               \
    unsigned long long cur = __shfl(K, (W));                                  \
    if ((W) + 1 < 64) { LOAD_D(DNXT, (W) + 1); LOAD_TILE(NXTB, (W) + 1); }    \
    unsigned long long active = __ballot((DCUR) != 0ull) & cur;               \
    while (active) {                                                          \
        int _kk = __ffsll((long long)active) - 1;                             \
        unsigned long long dk = __shfl((DCUR), _kk);                          \
        cur &= ~dk; active &= ~dk; active &= ~(1ull << _kk);                  \
    }                                                                         \
    unsigned long long sup = 0ull;                                            \
    _Pragma("unroll")                                                         \
    for (int _k = 0; _k < 64; _k++)                                           \
        sup |= ((cur >> _k) & 1ull) ? CURB[_k] : 0ull;                        \
    K &= ~sup;                                                                \
} while (0)

__global__ void __launch_bounds__(64, 1) nms_kernel(const unsigned long long* __restrict__ mask,
                                                    unsigned long long* __restrict__ keep_out) {
    int b = blockIdx.x;
    int lane = threadIdx.x;  // 64 lanes, lane owns keep word `lane`
    const unsigned long long* Mb = mask + (size_t)b * PRE_NMS * 64;
    unsigned long long K = ~0ull;
    unsigned long long bufA[64], bufB[64];
    unsigned long long da = 0ull, db = 0ull;
    LOAD_D(da, 0);
    LOAD_TILE(bufA, 0);
    for (int w = 0; w < 64; w += 2) {
        PROCESS(w, bufA, da, bufB, db);
        PROCESS(w + 1, bufB, db, bufA, da);
    }
    keep_out[b * 64 + lane] = K;
}

// ---------------- select top-500 and write output ----------------
__global__ void select_write_kernel(const unsigned long long* __restrict__ keep,
                                    const float* __restrict__ boxes,
                                    const float* __restrict__ s_top,
                                    float* __restrict__ out) {
    int b = blockIdx.x;
    __shared__ int cnts[64];
    __shared__ int bases[65];
    __shared__ int sel[POST_NMS];
    int t = threadIdx.x;  // 512
    if (t < 64) cnts[t] = __popcll(keep[b * 64 + t]);
    __syncthreads();
    if (t == 0) {
        int acc = 0;
        for (int w = 0; w < 64; w++) { bases[w] = acc; acc += cnts[w]; }
        bases[64] = acc;
    }
    __syncthreads();
    if (t < 64) {
        unsigned long long kw = keep[b * 64 + t];
        int K_total = bases[64];
        int kr = bases[t];
        int ur = t * 64 - bases[t];
        for (int k = 0; k < 64; k++) {
            int i = t * 64 + k;
            if ((kw >> k) & 1ull) {
                if (kr < POST_NMS) sel[kr] = i;
                kr++;
            } else {
                int pos = K_total + ur;
                if (pos < POST_NMS) sel[pos] = i;
                ur++;
            }
        }
    }
    __syncthreads();
    for (int r = t; r < POST_NMS; r += 512) {
        int i = sel[r];
        const float* bx = boxes + ((size_t)b * PRE_NMS + i) * 7;
        float* o = out + ((size_t)b * POST_NMS + r) * 8;
#pragma unroll
        for (int c = 0; c < 7; c++) o[c] = bx[c];
        o[7] = s_top[b * PRE_NMS + i];
    }
}

extern "C" void kernel_launch(void* const* d_in, const int* in_sizes, int n_in,
                              void* d_out, int out_size, void* d_ws, size_t ws_size,
                              hipStream_t stream) {
    const float* anchors = (const float*)d_in[0];
    const float* obj = (const float*)d_in[1];
    const float* reg = (const float*)d_in[2];
    float* out = (float*)d_out;
    const int A = in_sizes[1] / B_IMG;

    auto align = [](size_t x) { return (x + 255) & ~(size_t)255; };
    char* p = (char*)d_ws;
    uint2* state = (uint2*)p;                 p += align(B_IMG * sizeof(uint2));
    unsigned* hist = (unsigned*)p;            p += align(4 * B_IMG * 256 * sizeof(unsigned));
    unsigned* count = (unsigned*)p;           p += align(B_IMG * sizeof(unsigned));
    unsigned long long* cand = (unsigned long long*)p; p += align((size_t)B_IMG * CAND_CAP * 8);
    unsigned* topk = (unsigned*)p;            p += align((size_t)B_IMG * PRE_NMS * 4);
    float* s_top = (float*)p;                 p += align((size_t)B_IMG * PRE_NMS * 4);
    float* boxes = (float*)p;                 p += align((size_t)B_IMG * PRE_NMS * 7 * 4);
    float* X1 = (float*)p;                    p += align((size_t)B_IMG * PRE_NMS * 4);
    float* X2 = (float*)p;                    p += align((size_t)B_IMG * PRE_NMS * 4);
    float* Y1 = (float*)p;                    p += align((size_t)B_IMG * PRE_NMS * 4);
    float* Y2 = (float*)p;                    p += align((size_t)B_IMG * PRE_NMS * 4);
    float* AREA = (float*)p;                  p += align((size_t)B_IMG * PRE_NMS * 4);
    unsigned long long* mask = (unsigned long long*)p; p += align((size_t)B_IMG * PRE_NMS * 64 * 8);
    unsigned long long* keep = (unsigned long long*)p; p += align((size_t)B_IMG * 64 * 8);

    init_kernel<<<16, 256, 0, stream>>>(state, hist, count);
    for (int pass = 0; pass < 4; pass++) {
        hist_kernel<<<dim3(256, B_IMG), 256, 0, stream>>>(obj, state, hist, pass, A);
        scan_kernel<<<1, 64, 0, stream>>>(state, hist, pass);
    }
    gather_kernel<<<dim3(256, B_IMG), 256, 0, stream>>>(obj, state, cand, count, A);
    sort_kernel<<<B_IMG, 1024, 0, stream>>>(cand, count, topk, obj, s_top, A);
    decode_kernel<<<dim3(PRE_NMS / 256, B_IMG), 256, 0, stream>>>(anchors, reg, topk, boxes,
                                                                  X1, X2, Y1, Y2, AREA, A);
    mask_kernel<<<dim3(PRE_NMS * 64 / 256, B_IMG), 256, 0, stream>>>(X1, X2, Y1, Y2, AREA, mask);
    nms_kernel<<<B_IMG, 64, 0, stream>>>(mask, keep);
    select_write_kernel<<<B_IMG, 512, 0, stream>>>(keep, boxes, s_top, out);
}

// Round 3
// 455.260 us; speedup vs baseline: 2.4415x; 1.3685x over previous
//
#include <hip/hip_runtime.h>
#include <hip/hip_bf16.h>

#define B_IMG 4
#define PRE_NMS 4096
#define POST_NMS 500
#define CAND_CAP 8192
#define BND_CAP 65536

typedef unsigned long long ull;

__device__ __forceinline__ unsigned key_of(float f) {
    unsigned u = __float_as_uint(f);
    return (u & 0x80000000u) ? ~u : (u | 0x80000000u);
}

// ---------------- init ----------------
// count[0..3] = cand count per image (written by refine)
// count[4..7] = boundary-list count per image (atomic in compact)
__global__ void init_kernel(uint2* state, unsigned* hist, unsigned* count) {
    int t = blockIdx.x * blockDim.x + threadIdx.x;
    if (t < B_IMG) state[t] = make_uint2(0u, (unsigned)PRE_NMS);
    if (t < 2 * B_IMG) count[t] = 0u;
    if (t < B_IMG * 256) hist[t] = 0u;
}

// ---------------- pass-0 histogram (top byte), ballot-aggregated ----------------
__global__ void hist0_kernel(const float* __restrict__ obj, unsigned* __restrict__ hist, int A) {
    int b = blockIdx.y;
    __shared__ unsigned h[256];
    int t = threadIdx.x;
    int lane = t & 63;
    if (t < 256) h[t] = 0u;
    __syncthreads();
    const float* o = obj + (size_t)b * A;
    int stride = gridDim.x * blockDim.x;
    for (int i = blockIdx.x * blockDim.x + t;; i += stride) {
        bool valid = (i < A);
        ull vm = __ballot(valid);
        if (!vm) break;
        unsigned bin = valid ? (key_of(o[i]) >> 24) : 0xFFFFFFFFu;
        ull active = vm;
        while (active) {
            int leader = __ffsll((long long)active) - 1;
            unsigned lb = __shfl(bin, leader);
            ull m = __ballot(bin == lb) & active;
            if (lane == leader) atomicAdd(&h[lb], (unsigned)__popcll(m));
            active &= ~m;
        }
    }
    __syncthreads();
    if (t < 256 && h[t]) atomicAdd(&hist[b * 256 + t], h[t]);
}

// ---------------- pass-0 scan: boundary digit d0 + residual k ----------------
__global__ void scan0_kernel(uint2* state, const unsigned* __restrict__ hist) {
    int b = threadIdx.x;
    if (b < B_IMG) {
        const unsigned* h = hist + b * 256;
        unsigned kneed = state[b].y;
        unsigned cum = 0;
        int d;
        for (d = 255; d > 0; d--) {
            unsigned c = h[d];
            if (cum + c >= kneed) break;
            cum += c;
        }
        state[b].x = (unsigned)d;
        state[b].y = kneed - cum;
    }
}

// ---------------- compact: emit all elements with top byte >= d0 ----------------
__global__ void compact_kernel(const float* __restrict__ obj, const uint2* __restrict__ state,
                               ull* __restrict__ bnd, unsigned* __restrict__ count, int A) {
    int b = blockIdx.y;
    unsigned d0 = state[b].x;
    __shared__ ull buf[2048];
    __shared__ unsigned lcnt, base;
    int t = threadIdx.x;
    if (t == 0) lcnt = 0u;
    __syncthreads();
    const float* o = obj + (size_t)b * A;
    int stride = gridDim.x * blockDim.x;
    for (int i = blockIdx.x * blockDim.x + t; i < A; i += stride) {
        unsigned key = key_of(o[i]);
        if ((key >> 24) >= d0) {
            unsigned p = atomicAdd(&lcnt, 1u);
            if (p < 2048u)
                buf[p] = ((ull)key << 32) | (unsigned)(0xFFFFFFFFu - (unsigned)i);
        }
    }
    __syncthreads();
    unsigned c = lcnt < 2048u ? lcnt : 2048u;
    if (t == 0) base = atomicAdd(&count[B_IMG + b], c);
    __syncthreads();
    for (unsigned p = t; p < c; p += blockDim.x) {
        unsigned pos = base + p;
        if (pos < BND_CAP) bnd[(size_t)b * BND_CAP + pos] = buf[p];
    }
}

// ---------------- refine: radix passes 1-3 + threshold gather, one block/image ----------------
__global__ void __launch_bounds__(1024) refine_kernel(const ull* __restrict__ bnd,
                                                      uint2* state,
                                                      ull* __restrict__ cand,
                                                      unsigned* __restrict__ count) {
    int b = blockIdx.x;
    __shared__ unsigned h[256];
    __shared__ unsigned sh_prefix, sh_kneed, sh_pos;
    int t = threadIdx.x;
    unsigned n = count[B_IMG + b];
    if (n > BND_CAP) n = BND_CAP;
    const ull* L = bnd + (size_t)b * BND_CAP;
    if (t == 0) { sh_prefix = state[b].x; sh_kneed = state[b].y; sh_pos = 0u; }
    for (int pass = 1; pass < 4; pass++) {
        if (t < 256) h[t] = 0u;
        __syncthreads();
        unsigned prefix = sh_prefix;
        int sh = 32 - 8 * pass;
        int dsh = 24 - 8 * pass;
        for (unsigned i = t; i < n; i += 1024) {
            unsigned key = (unsigned)(L[i] >> 32);
            if ((key >> sh) == prefix) atomicAdd(&h[(key >> dsh) & 255u], 1u);
        }
        __syncthreads();
        if (t == 0) {
            unsigned kneed = sh_kneed, cum = 0;
            int d;
            for (d = 255; d > 0; d--) {
                unsigned c = h[d];
                if (cum + c >= kneed) break;
                cum += c;
            }
            sh_prefix = (prefix << 8) | (unsigned)d;
            sh_kneed = kneed - cum;
        }
        __syncthreads();
    }
    unsigned T = sh_prefix;
    for (unsigned i = t; i < n; i += 1024) {
        ull v = L[i];
        if ((unsigned)(v >> 32) >= T) {
            unsigned p = atomicAdd(&sh_pos, 1u);
            if (p < CAND_CAP) cand[(size_t)b * CAND_CAP + p] = v;
        }
    }
    __syncthreads();
    if (t == 0) count[b] = sh_pos < CAND_CAP ? sh_pos : CAND_CAP;
}

// ---------------- bitonic sort of candidates (desc), emit topk ----------------
__global__ void __launch_bounds__(1024) sort_kernel(const ull* __restrict__ cand,
                                                    const unsigned* __restrict__ count,
                                                    unsigned* __restrict__ topk_idx,
                                                    const float* __restrict__ obj,
                                                    float* __restrict__ s_top, int A) {
    __shared__ ull s[CAND_CAP];
    int b = blockIdx.x;
    int t = threadIdx.x;
    unsigned cnt = count[b];
    if (cnt > CAND_CAP) cnt = CAND_CAP;
    const ull* C = cand + (size_t)b * CAND_CAP;
    for (int i = t; i < CAND_CAP; i += 1024) s[i] = (i < (int)cnt) ? C[i] : 0ull;
    __syncthreads();
    for (int k = 2; k <= CAND_CAP; k <<= 1) {
        for (int j = k >> 1; j > 0; j >>= 1) {
            for (int i = t; i < CAND_CAP; i += 1024) {
                int l = i ^ j;
                if (l > i) {
                    ull a = s[i], c = s[l];
                    bool up = ((i & k) == 0);
                    if (up ? (a < c) : (a > c)) { s[i] = c; s[l] = a; }
                }
            }
            __syncthreads();
        }
    }
    for (int r = t; r < PRE_NMS; r += 1024) {
        ull v = s[r];
        unsigned idx = 0xFFFFFFFFu - (unsigned)(v & 0xFFFFFFFFull);
        topk_idx[b * PRE_NMS + r] = idx;
        float x = obj[(size_t)b * A + idx];
        s_top[b * PRE_NMS + r] = 1.0f / (1.0f + expf(-x));
    }
}

// ---------------- decode boxes ----------------
__global__ void decode_kernel(const float* __restrict__ anchors, const float* __restrict__ reg,
                              const unsigned* __restrict__ topk_idx, float* __restrict__ boxes,
                              float* __restrict__ X1, float* __restrict__ X2,
                              float* __restrict__ Y1, float* __restrict__ Y2,
                              float* __restrict__ AREA, int A) {
    int b = blockIdx.y;
    int r = blockIdx.x * 256 + threadIdx.x;
    if (r >= PRE_NMS) return;
    unsigned idx = topk_idx[b * PRE_NMS + r];
    const float* an = anchors + ((size_t)b * A + idx) * 7;
    const float* rg = reg + ((size_t)b * A + idx) * 7;
    float xa = an[0], ya = an[1], za = an[2], wa = an[3], la = an[4], ha = an[5], ra = an[6];
    float diag = sqrtf(wa * wa + la * la);
    float xg = rg[0] * diag + xa;
    float yg = rg[1] * diag + ya;
    float zg = rg[2] * ha + za;
    float wg = expf(rg[3]) * wa;
    float lg = expf(rg[4]) * la;
    float hg = expf(rg[5]) * ha;
    float rr = rg[6] + ra;
    float* o = boxes + ((size_t)b * PRE_NMS + r) * 7;
    o[0] = xg; o[1] = yg; o[2] = zg; o[3] = wg; o[4] = lg; o[5] = hg; o[6] = rr;
    int q = b * PRE_NMS + r;
    X1[q] = xg - wg * 0.5f;
    X2[q] = xg + wg * 0.5f;
    Y1[q] = yg - lg * 0.5f;
    Y2[q] = yg + lg * 0.5f;
    AREA[q] = wg * lg;
}

// ---------------- suppression bitmask ----------------
__global__ void mask_kernel(const float* __restrict__ X1, const float* __restrict__ X2,
                            const float* __restrict__ Y1, const float* __restrict__ Y2,
                            const float* __restrict__ AREA, ull* __restrict__ mask) {
    int b = blockIdx.y;
    int t = blockIdx.x * 256 + threadIdx.x;   // 1024 blocks * 256 = 262144 = 4096*64
    int i = t & (PRE_NMS - 1);
    int w = t >> 12;
    int q0 = b * PRE_NMS;
    float x1i = X1[q0 + i], x2i = X2[q0 + i];
    float y1i = Y1[q0 + i], y2i = Y2[q0 + i];
    float ai = AREA[q0 + i];
    ull word = 0ull;
    int jbase = w << 6;
#pragma unroll 4
    for (int k = 0; k < 64; k++) {
        int j = jbase + k;
        float iw = fminf(x2i, X2[q0 + j]) - fmaxf(x1i, X1[q0 + j]);
        iw = fmaxf(iw, 0.0f);
        float ih = fminf(y2i, Y2[q0 + j]) - fmaxf(y1i, Y1[q0 + j]);
        ih = fmaxf(ih, 0.0f);
        float inter = iw * ih;
        float den = ai + AREA[q0 + j] - inter + 1e-6f;
        float iou = inter / den;
        word |= ((ull)((iou > 0.7f) && (j > i))) << k;
    }
    mask[((size_t)b * PRE_NMS + i) * 64 + w] = word;
}

// ---------------- tiled greedy NMS resolve ----------------
#define LOAD_TILE(BUF, WT) do {                                               \
    const ull* _base = Mb + ((size_t)(WT) << 12) + lane;                      \
    _Pragma("unroll")                                                         \
    for (int _k = 0; _k < 64; _k++) BUF[_k] = _base[(size_t)_k << 6];         \
} while (0)

#define LOAD_D(DST, WT) (DST) = Mb[((size_t)(WT) << 12) + ((size_t)lane << 6) + (WT)]

#define PROCESS(W, CURB, DCUR, NXTB, DNXT) do {                               \
    ull cur = __shfl(K, (W));                                                 \
    if ((W) + 1 < 64) { LOAD_D(DNXT, (W) + 1); LOAD_TILE(NXTB, (W) + 1); }    \
    ull active = __ballot((DCUR) != 0ull) & cur;                              \
    while (active) {                                                          \
        int _kk = __ffsll((long long)active) - 1;                             \
        ull dk = __shfl((DCUR), _kk);                                         \
        cur &= ~dk; active &= ~dk; active &= ~(1ull << _kk);                  \
    }                                                                         \
    ull sup = 0ull;                                                           \
    _Pragma("unroll")                                                         \
    for (int _k = 0; _k < 64; _k++)                                           \
        sup |= ((cur >> _k) & 1ull) ? CURB[_k] : 0ull;                        \
    K &= ~sup;                                                                \
} while (0)

__global__ void __launch_bounds__(64, 1) nms_kernel(const ull* __restrict__ mask,
                                                    ull* __restrict__ keep_out) {
    int b = blockIdx.x;
    int lane = threadIdx.x;  // 64 lanes, lane owns keep word `lane`
    const ull* Mb = mask + (size_t)b * PRE_NMS * 64;
    ull K = ~0ull;
    ull bufA[64], bufB[64];
    ull da = 0ull, db = 0ull;
    LOAD_D(da, 0);
    LOAD_TILE(bufA, 0);
    for (int w = 0; w < 64; w += 2) {
        PROCESS(w, bufA, da, bufB, db);
        PROCESS(w + 1, bufB, db, bufA, da);
    }
    keep_out[b * 64 + lane] = K;
}

// ---------------- select top-500 and write output ----------------
__global__ void select_write_kernel(const ull* __restrict__ keep,
                                    const float* __restrict__ boxes,
                                    const float* __restrict__ s_top,
                                    float* __restrict__ out) {
    int b = blockIdx.x;
    __shared__ int cnts[64];
    __shared__ int bases[65];
    __shared__ int sel[POST_NMS];
    int t = threadIdx.x;  // 512
    if (t < 64) cnts[t] = __popcll(keep[b * 64 + t]);
    __syncthreads();
    if (t == 0) {
        int acc = 0;
        for (int w = 0; w < 64; w++) { bases[w] = acc; acc += cnts[w]; }
        bases[64] = acc;
    }
    __syncthreads();
    if (t < 64) {
        ull kw = keep[b * 64 + t];
        int K_total = bases[64];
        int kr = bases[t];
        int ur = t * 64 - bases[t];
        for (int k = 0; k < 64; k++) {
            int i = t * 64 + k;
            if ((kw >> k) & 1ull) {
                if (kr < POST_NMS) sel[kr] = i;
                kr++;
            } else {
                int pos = K_total + ur;
                if (pos < POST_NMS) sel[pos] = i;
                ur++;
            }
        }
    }
    __syncthreads();
    for (int r = t; r < POST_NMS; r += 512) {
        int i = sel[r];
        const float* bx = boxes + ((size_t)b * PRE_NMS + i) * 7;
        float* o = out + ((size_t)b * POST_NMS + r) * 8;
#pragma unroll
        for (int c = 0; c < 7; c++) o[c] = bx[c];
        o[7] = s_top[b * PRE_NMS + i];
    }
}

extern "C" void kernel_launch(void* const* d_in, const int* in_sizes, int n_in,
                              void* d_out, int out_size, void* d_ws, size_t ws_size,
                              hipStream_t stream) {
    const float* anchors = (const float*)d_in[0];
    const float* obj = (const float*)d_in[1];
    const float* reg = (const float*)d_in[2];
    float* out = (float*)d_out;
    const int A = in_sizes[1] / B_IMG;

    auto align = [](size_t x) { return (x + 255) & ~(size_t)255; };
    char* p = (char*)d_ws;
    uint2* state = (uint2*)p;     p += align(B_IMG * sizeof(uint2));
    unsigned* hist = (unsigned*)p; p += align(B_IMG * 256 * sizeof(unsigned));
    unsigned* count = (unsigned*)p; p += align(2 * B_IMG * sizeof(unsigned));
    ull* cand = (ull*)p;          p += align((size_t)B_IMG * CAND_CAP * 8);
    ull* bnd = (ull*)p;           p += align((size_t)B_IMG * BND_CAP * 8);
    unsigned* topk = (unsigned*)p; p += align((size_t)B_IMG * PRE_NMS * 4);
    float* s_top = (float*)p;     p += align((size_t)B_IMG * PRE_NMS * 4);
    float* boxes = (float*)p;     p += align((size_t)B_IMG * PRE_NMS * 7 * 4);
    float* X1 = (float*)p;        p += align((size_t)B_IMG * PRE_NMS * 4);
    float* X2 = (float*)p;        p += align((size_t)B_IMG * PRE_NMS * 4);
    float* Y1 = (float*)p;        p += align((size_t)B_IMG * PRE_NMS * 4);
    float* Y2 = (float*)p;        p += align((size_t)B_IMG * PRE_NMS * 4);
    float* AREA = (float*)p;      p += align((size_t)B_IMG * PRE_NMS * 4);
    ull* mask = (ull*)p;          p += align((size_t)B_IMG * PRE_NMS * 64 * 8);
    ull* keep = (ull*)p;          p += align((size_t)B_IMG * 64 * 8);

    init_kernel<<<4, 256, 0, stream>>>(state, hist, count);
    hist0_kernel<<<dim3(256, B_IMG), 256, 0, stream>>>(obj, hist, A);
    scan0_kernel<<<1, 64, 0, stream>>>(state, hist);
    compact_kernel<<<dim3(256, B_IMG), 256, 0, stream>>>(obj, state, bnd, count, A);
    refine_kernel<<<B_IMG, 1024, 0, stream>>>(bnd, state, cand, count);
    sort_kernel<<<B_IMG, 1024, 0, stream>>>(cand, count, topk, obj, s_top, A);
    decode_kernel<<<dim3(PRE_NMS / 256, B_IMG), 256, 0, stream>>>(anchors, reg, topk, boxes,
                                                                  X1, X2, Y1, Y2, AREA, A);
    mask_kernel<<<dim3(PRE_NMS * 64 / 256, B_IMG), 256, 0, stream>>>(X1, X2, Y1, Y2, AREA, mask);
    nms_kernel<<<B_IMG, 64, 0, stream>>>(mask, keep);
    select_write_kernel<<<B_IMG, 512, 0, stream>>>(keep, boxes, s_top, out);
}

// Round 4
// 390.786 us; speedup vs baseline: 2.8443x; 1.1650x over previous
//
#include <hip/hip_runtime.h>
#include <hip/hip_bf16.h>

#define B_IMG 4
#define PRE_NMS 4096
#define POST_NMS 500
#define CAND_CAP 8192
#define BND_CAP 65536

typedef unsigned long long ull;

__device__ __forceinline__ unsigned key_of(float f) {
    unsigned u = __float_as_uint(f);
    return (u & 0x80000000u) ? ~u : (u | 0x80000000u);
}

// ---------------- init ----------------
// count[0..3] = cand count per image (written by refine)
// count[4..7] = boundary-list count per image (atomic in compact)
__global__ void init_kernel(uint2* state, unsigned* hist, unsigned* count) {
    int t = blockIdx.x * blockDim.x + threadIdx.x;
    if (t < B_IMG) state[t] = make_uint2(0u, (unsigned)PRE_NMS);
    if (t < 2 * B_IMG) count[t] = 0u;
    if (t < B_IMG * 256) hist[t] = 0u;
}

// ---------------- pass-0 histogram (top byte), ballot-aggregated ----------------
__global__ void hist0_kernel(const float* __restrict__ obj, unsigned* __restrict__ hist, int A) {
    int b = blockIdx.y;
    __shared__ unsigned h[256];
    int t = threadIdx.x;
    int lane = t & 63;
    if (t < 256) h[t] = 0u;
    __syncthreads();
    const float* o = obj + (size_t)b * A;
    int stride = gridDim.x * blockDim.x;
    for (int i = blockIdx.x * blockDim.x + t;; i += stride) {
        bool valid = (i < A);
        ull vm = __ballot(valid);
        if (!vm) break;
        unsigned bin = valid ? (key_of(o[i]) >> 24) : 0xFFFFFFFFu;
        ull active = vm;
        while (active) {
            int leader = __ffsll((long long)active) - 1;
            unsigned lb = __shfl(bin, leader);
            ull m = __ballot(bin == lb) & active;
            if (lane == leader) atomicAdd(&h[lb], (unsigned)__popcll(m));
            active &= ~m;
        }
    }
    __syncthreads();
    if (t < 256 && h[t]) atomicAdd(&hist[b * 256 + t], h[t]);
}

// ---------------- pass-0 scan: boundary digit d0 + residual k ----------------
__global__ void scan0_kernel(uint2* state, const unsigned* __restrict__ hist) {
    int b = threadIdx.x;
    if (b < B_IMG) {
        const unsigned* h = hist + b * 256;
        unsigned kneed = state[b].y;
        unsigned cum = 0;
        int d;
        for (d = 255; d > 0; d--) {
            unsigned c = h[d];
            if (cum + c >= kneed) break;
            cum += c;
        }
        state[b].x = (unsigned)d;
        state[b].y = kneed - cum;
    }
}

// ---------------- compact: emit all elements with top byte >= d0 ----------------
__global__ void compact_kernel(const float* __restrict__ obj, const uint2* __restrict__ state,
                               ull* __restrict__ bnd, unsigned* __restrict__ count, int A) {
    int b = blockIdx.y;
    unsigned d0 = state[b].x;
    __shared__ ull buf[2048];
    __shared__ unsigned lcnt, base;
    int t = threadIdx.x;
    if (t == 0) lcnt = 0u;
    __syncthreads();
    const float* o = obj + (size_t)b * A;
    int stride = gridDim.x * blockDim.x;
    for (int i = blockIdx.x * blockDim.x + t; i < A; i += stride) {
        unsigned key = key_of(o[i]);
        if ((key >> 24) >= d0) {
            unsigned p = atomicAdd(&lcnt, 1u);
            if (p < 2048u)
                buf[p] = ((ull)key << 32) | (unsigned)(0xFFFFFFFFu - (unsigned)i);
        }
    }
    __syncthreads();
    unsigned c = lcnt < 2048u ? lcnt : 2048u;
    if (t == 0) base = atomicAdd(&count[B_IMG + b], c);
    __syncthreads();
    for (unsigned p = t; p < c; p += blockDim.x) {
        unsigned pos = base + p;
        if (pos < BND_CAP) bnd[(size_t)b * BND_CAP + pos] = buf[p];
    }
}

// ---------------- refine: radix passes 1-3 + threshold gather, one block/image ----------------
__global__ void __launch_bounds__(1024) refine_kernel(const ull* __restrict__ bnd,
                                                      uint2* state,
                                                      ull* __restrict__ cand,
                                                      unsigned* __restrict__ count) {
    int b = blockIdx.x;
    __shared__ unsigned h[256];
    __shared__ unsigned sh_prefix, sh_kneed, sh_pos;
    int t = threadIdx.x;
    unsigned n = count[B_IMG + b];
    if (n > BND_CAP) n = BND_CAP;
    const ull* L = bnd + (size_t)b * BND_CAP;
    if (t == 0) { sh_prefix = state[b].x; sh_kneed = state[b].y; sh_pos = 0u; }
    for (int pass = 1; pass < 4; pass++) {
        if (t < 256) h[t] = 0u;
        __syncthreads();
        unsigned prefix = sh_prefix;
        int sh = 32 - 8 * pass;
        int dsh = 24 - 8 * pass;
        for (unsigned i = t; i < n; i += 1024) {
            unsigned key = (unsigned)(L[i] >> 32);
            if ((key >> sh) == prefix) atomicAdd(&h[(key >> dsh) & 255u], 1u);
        }
        __syncthreads();
        if (t == 0) {
            unsigned kneed = sh_kneed, cum = 0;
            int d;
            for (d = 255; d > 0; d--) {
                unsigned c = h[d];
                if (cum + c >= kneed) break;
                cum += c;
            }
            sh_prefix = (prefix << 8) | (unsigned)d;
            sh_kneed = kneed - cum;
        }
        __syncthreads();
    }
    unsigned T = sh_prefix;
    for (unsigned i = t; i < n; i += 1024) {
        ull v = L[i];
        if ((unsigned)(v >> 32) >= T) {
            unsigned p = atomicAdd(&sh_pos, 1u);
            if (p < CAND_CAP) cand[(size_t)b * CAND_CAP + p] = v;
        }
    }
    __syncthreads();
    if (t == 0) count[b] = sh_pos < CAND_CAP ? sh_pos : CAND_CAP;
}

// ---------------- rank: exact stable top-k position via O(n^2) count ----------------
// Composites are unique, so rank = #{j : comp[j] > comp[i]} is the exact position
// in the descending stable order (key desc, original index asc). Barrier-free,
// spread over 32 blocks/image; inner loop is a uniform LDS broadcast read.
__global__ void __launch_bounds__(256) rank_kernel(const ull* __restrict__ cand,
                                                   const unsigned* __restrict__ count,
                                                   unsigned* __restrict__ topk_idx,
                                                   const float* __restrict__ obj,
                                                   float* __restrict__ s_top, int A) {
    __shared__ ull s[CAND_CAP];
    int b = blockIdx.y;
    int t = threadIdx.x;
    unsigned cnt = count[b];
    if (cnt > CAND_CAP) cnt = CAND_CAP;
    const ull* C = cand + (size_t)b * CAND_CAP;
    unsigned cntR = (cnt + 7u) & ~7u;
    for (unsigned i = t; i < cntR; i += 256) s[i] = (i < cnt) ? C[i] : 0ull;
    __syncthreads();
    unsigned c = blockIdx.x * 256 + t;
    if (c >= cnt) return;
    ull me = s[c];
    unsigned rank = 0;
#pragma unroll 1
    for (unsigned j = 0; j < cntR; j += 8) {
        rank += (unsigned)(s[j]     > me) + (unsigned)(s[j + 1] > me)
              + (unsigned)(s[j + 2] > me) + (unsigned)(s[j + 3] > me)
              + (unsigned)(s[j + 4] > me) + (unsigned)(s[j + 5] > me)
              + (unsigned)(s[j + 6] > me) + (unsigned)(s[j + 7] > me);
    }
    if (rank < PRE_NMS) {
        unsigned idx = 0xFFFFFFFFu - (unsigned)(me & 0xFFFFFFFFull);
        topk_idx[b * PRE_NMS + rank] = idx;
        float x = obj[(size_t)b * A + idx];
        s_top[b * PRE_NMS + rank] = 1.0f / (1.0f + expf(-x));
    }
}

// ---------------- decode boxes ----------------
__global__ void decode_kernel(const float* __restrict__ anchors, const float* __restrict__ reg,
                              const unsigned* __restrict__ topk_idx, float* __restrict__ boxes,
                              float* __restrict__ X1, float* __restrict__ X2,
                              float* __restrict__ Y1, float* __restrict__ Y2,
                              float* __restrict__ AREA, int A) {
    int b = blockIdx.y;
    int r = blockIdx.x * 256 + threadIdx.x;
    if (r >= PRE_NMS) return;
    unsigned idx = topk_idx[b * PRE_NMS + r];
    const float* an = anchors + ((size_t)b * A + idx) * 7;
    const float* rg = reg + ((size_t)b * A + idx) * 7;
    float xa = an[0], ya = an[1], za = an[2], wa = an[3], la = an[4], ha = an[5], ra = an[6];
    float diag = sqrtf(wa * wa + la * la);
    float xg = rg[0] * diag + xa;
    float yg = rg[1] * diag + ya;
    float zg = rg[2] * ha + za;
    float wg = expf(rg[3]) * wa;
    float lg = expf(rg[4]) * la;
    float hg = expf(rg[5]) * ha;
    float rr = rg[6] + ra;
    float* o = boxes + ((size_t)b * PRE_NMS + r) * 7;
    o[0] = xg; o[1] = yg; o[2] = zg; o[3] = wg; o[4] = lg; o[5] = hg; o[6] = rr;
    int q = b * PRE_NMS + r;
    X1[q] = xg - wg * 0.5f;
    X2[q] = xg + wg * 0.5f;
    Y1[q] = yg - lg * 0.5f;
    Y2[q] = yg + lg * 0.5f;
    AREA[q] = wg * lg;
}

// ---------------- suppression bitmask ----------------
__global__ void mask_kernel(const float* __restrict__ X1, const float* __restrict__ X2,
                            const float* __restrict__ Y1, const float* __restrict__ Y2,
                            const float* __restrict__ AREA, ull* __restrict__ mask) {
    int b = blockIdx.y;
    int t = blockIdx.x * 256 + threadIdx.x;   // 1024 blocks * 256 = 262144 = 4096*64
    int i = t & (PRE_NMS - 1);
    int w = t >> 12;
    int q0 = b * PRE_NMS;
    float x1i = X1[q0 + i], x2i = X2[q0 + i];
    float y1i = Y1[q0 + i], y2i = Y2[q0 + i];
    float ai = AREA[q0 + i];
    ull word = 0ull;
    int jbase = w << 6;
#pragma unroll 4
    for (int k = 0; k < 64; k++) {
        int j = jbase + k;
        float iw = fminf(x2i, X2[q0 + j]) - fmaxf(x1i, X1[q0 + j]);
        iw = fmaxf(iw, 0.0f);
        float ih = fminf(y2i, Y2[q0 + j]) - fmaxf(y1i, Y1[q0 + j]);
        ih = fmaxf(ih, 0.0f);
        float inter = iw * ih;
        float den = ai + AREA[q0 + j] - inter + 1e-6f;
        float iou = inter / den;
        word |= ((ull)((iou > 0.7f) && (j > i))) << k;
    }
    mask[((size_t)b * PRE_NMS + i) * 64 + w] = word;
}

// ---------------- tiled greedy NMS resolve ----------------
#define LOAD_TILE(BUF, WT) do {                                               \
    const ull* _base = Mb + ((size_t)(WT) << 12) + lane;                      \
    _Pragma("unroll")                                                         \
    for (int _k = 0; _k < 64; _k++) BUF[_k] = _base[(size_t)_k << 6];         \
} while (0)

#define LOAD_D(DST, WT) (DST) = Mb[((size_t)(WT) << 12) + ((size_t)lane << 6) + (WT)]

#define PROCESS(W, CURB, DCUR, NXTB, DNXT) do {                               \
    ull cur = __shfl(K, (W));                                                 \
    if ((W) + 1 < 64) { LOAD_D(DNXT, (W) + 1); LOAD_TILE(NXTB, (W) + 1); }    \
    ull active = __ballot((DCUR) != 0ull) & cur;                              \
    while (active) {                                                          \
        int _kk = __ffsll((long long)active) - 1;                             \
        ull dk = __shfl((DCUR), _kk);                                         \
        cur &= ~dk; active &= ~dk; active &= ~(1ull << _kk);                  \
    }                                                                         \
    ull sup = 0ull;                                                           \
    _Pragma("unroll")                                                         \
    for (int _k = 0; _k < 64; _k++)                                           \
        sup |= ((cur >> _k) & 1ull) ? CURB[_k] : 0ull;                        \
    K &= ~sup;                                                                \
} while (0)

__global__ void __launch_bounds__(64, 1) nms_kernel(const ull* __restrict__ mask,
                                                    ull* __restrict__ keep_out) {
    int b = blockIdx.x;
    int lane = threadIdx.x;  // 64 lanes, lane owns keep word `lane`
    const ull* Mb = mask + (size_t)b * PRE_NMS * 64;
    ull K = ~0ull;
    ull bufA[64], bufB[64];
    ull da = 0ull, db = 0ull;
    LOAD_D(da, 0);
    LOAD_TILE(bufA, 0);
    for (int w = 0; w < 64; w += 2) {
        PROCESS(w, bufA, da, bufB, db);
        PROCESS(w + 1, bufB, db, bufA, da);
    }
    keep_out[b * 64 + lane] = K;
}

// ---------------- select top-500 and write output ----------------
__global__ void select_write_kernel(const ull* __restrict__ keep,
                                    const float* __restrict__ boxes,
                                    const float* __restrict__ s_top,
                                    float* __restrict__ out) {
    int b = blockIdx.x;
    __shared__ int cnts[64];
    __shared__ int bases[65];
    __shared__ int sel[POST_NMS];
    int t = threadIdx.x;  // 512
    if (t < 64) cnts[t] = __popcll(keep[b * 64 + t]);
    __syncthreads();
    if (t == 0) {
        int acc = 0;
        for (int w = 0; w < 64; w++) { bases[w] = acc; acc += cnts[w]; }
        bases[64] = acc;
    }
    __syncthreads();
    if (t < 64) {
        ull kw = keep[b * 64 + t];
        int K_total = bases[64];
        int kr = bases[t];
        int ur = t * 64 - bases[t];
        for (int k = 0; k < 64; k++) {
            int i = t * 64 + k;
            if ((kw >> k) & 1ull) {
                if (kr < POST_NMS) sel[kr] = i;
                kr++;
            } else {
                int pos = K_total + ur;
                if (pos < POST_NMS) sel[pos] = i;
                ur++;
            }
        }
    }
    __syncthreads();
    for (int r = t; r < POST_NMS; r += 512) {
        int i = sel[r];
        const float* bx = boxes + ((size_t)b * PRE_NMS + i) * 7;
        float* o = out + ((size_t)b * POST_NMS + r) * 8;
#pragma unroll
        for (int c = 0; c < 7; c++) o[c] = bx[c];
        o[7] = s_top[b * PRE_NMS + i];
    }
}

extern "C" void kernel_launch(void* const* d_in, const int* in_sizes, int n_in,
                              void* d_out, int out_size, void* d_ws, size_t ws_size,
                              hipStream_t stream) {
    const float* anchors = (const float*)d_in[0];
    const float* obj = (const float*)d_in[1];
    const float* reg = (const float*)d_in[2];
    float* out = (float*)d_out;
    const int A = in_sizes[1] / B_IMG;

    auto align = [](size_t x) { return (x + 255) & ~(size_t)255; };
    char* p = (char*)d_ws;
    uint2* state = (uint2*)p;     p += align(B_IMG * sizeof(uint2));
    unsigned* hist = (unsigned*)p; p += align(B_IMG * 256 * sizeof(unsigned));
    unsigned* count = (unsigned*)p; p += align(2 * B_IMG * sizeof(unsigned));
    ull* cand = (ull*)p;          p += align((size_t)B_IMG * CAND_CAP * 8);
    ull* bnd = (ull*)p;           p += align((size_t)B_IMG * BND_CAP * 8);
    unsigned* topk = (unsigned*)p; p += align((size_t)B_IMG * PRE_NMS * 4);
    float* s_top = (float*)p;     p += align((size_t)B_IMG * PRE_NMS * 4);
    float* boxes = (float*)p;     p += align((size_t)B_IMG * PRE_NMS * 7 * 4);
    float* X1 = (float*)p;        p += align((size_t)B_IMG * PRE_NMS * 4);
    float* X2 = (float*)p;        p += align((size_t)B_IMG * PRE_NMS * 4);
    float* Y1 = (float*)p;        p += align((size_t)B_IMG * PRE_NMS * 4);
    float* Y2 = (float*)p;        p += align((size_t)B_IMG * PRE_NMS * 4);
    float* AREA = (float*)p;      p += align((size_t)B_IMG * PRE_NMS * 4);
    ull* mask = (ull*)p;          p += align((size_t)B_IMG * PRE_NMS * 64 * 8);
    ull* keep = (ull*)p;          p += align((size_t)B_IMG * 64 * 8);

    init_kernel<<<4, 256, 0, stream>>>(state, hist, count);
    hist0_kernel<<<dim3(256, B_IMG), 256, 0, stream>>>(obj, hist, A);
    scan0_kernel<<<1, 64, 0, stream>>>(state, hist);
    compact_kernel<<<dim3(256, B_IMG), 256, 0, stream>>>(obj, state, bnd, count, A);
    refine_kernel<<<B_IMG, 1024, 0, stream>>>(bnd, state, cand, count);
    rank_kernel<<<dim3(CAND_CAP / 256, B_IMG), 256, 0, stream>>>(cand, count, topk, obj, s_top, A);
    decode_kernel<<<dim3(PRE_NMS / 256, B_IMG), 256, 0, stream>>>(anchors, reg, topk, boxes,
                                                                  X1, X2, Y1, Y2, AREA, A);
    mask_kernel<<<dim3(PRE_NMS * 64 / 256, B_IMG), 256, 0, stream>>>(X1, X2, Y1, Y2, AREA, mask);
    nms_kernel<<<B_IMG, 64, 0, stream>>>(mask, keep);
    select_write_kernel<<<B_IMG, 512, 0, stream>>>(keep, boxes, s_top, out);
}